// Round 6
// baseline (503.785 us; speedup 1.0000x reference)
//
#include <hip/hip_runtime.h>
#include <hip/hip_cooperative_groups.h>
#include <math.h>
#include <limits.h>

namespace cg = cooperative_groups;

// Problem constants (from reference): N=2e6, C=64, B=16, H=32.
#define NCH   64
#define NBAT  16
#define NHID  32
#define NGRP  4      // segment groups; 4 segments ~ 128 MB of x, fits L3
#define SPG   4      // segments per group (NBAT/NGRP)
#define NB    256    // blocks (1 per CU, cooperative co-residency)
#define NT    1024   // threads per block (16 waves)

typedef float f4 __attribute__((ext_vector_type(4)));

// Workspace layout (floats):
//   [0    .. 1023]  per-(b,c) sums
//   [1024 .. 2047]  per-(b,c) maxes
//   [2048 .. 2063]  per-b counts
//   [3088 .. 3103]  (as int) seg_start[b], INT_MAX if empty

__device__ __forceinline__ void atomicMaxF(float* addr, float v) {
    // Monotone-lattice trick: works for mixed signs, init must be -inf.
    if (v >= 0.0f) atomicMax((int*)addr, __float_as_int(v));
    else           atomicMin((unsigned int*)addr, __float_as_uint(v));
}

__device__ __forceinline__ int minseg(const int* ss, int k, int n) {
    int m = n;
    for (int b = k; b < NBAT; ++b) m = min(m, ss[b]);
    return m;
}

__device__ __forceinline__ void flush_seg(float* __restrict__ wsum,
                                          float* __restrict__ wmax,
                                          float* __restrict__ wcnt,
                                          int b, int c4,
                                          const float4& s, const float4& m, float cnt) {
    float* ps = wsum + b * NCH + c4 * 4;
    atomicAdd(ps + 0, s.x);
    atomicAdd(ps + 1, s.y);
    atomicAdd(ps + 2, s.z);
    atomicAdd(ps + 3, s.w);
    float* pm = wmax + b * NCH + c4 * 4;
    atomicMaxF(pm + 0, m.x);
    atomicMaxF(pm + 1, m.y);
    atomicMaxF(pm + 2, m.z);
    atomicMaxF(pm + 3, m.w);
    if (c4 == 0) atomicAdd(wcnt + b, cnt);
}

__global__ __launch_bounds__(NT, 4) void fused_kernel(
        const float* __restrict__ x, const int* __restrict__ bid,
        const float* __restrict__ W1, const float* __restrict__ b1,
        const float* __restrict__ W2, const float* __restrict__ b2,
        float* __restrict__ out, float* __restrict__ ws, int n) {
    cg::grid_group grid = cg::this_grid();
    const int t = threadIdx.x;
    const int blk = blockIdx.x;

    // LDS (~57 KB): combine buffers (reused as MLP scratch), weights, scales.
    __shared__ float4 ls[NT];
    __shared__ float4 lm[NT];
    __shared__ int    lb[NT];
    __shared__ float  lc[NT];
    __shared__ float  sW1[NHID * NCH];
    __shared__ float  sW2[NCH * NHID];
    __shared__ float  sb1[NHID];
    __shared__ float  sb2[NCH];
    __shared__ float  sscale[SPG * NCH];

    float* wsum = ws;
    float* wmax = ws + 1024;
    float* wcnt = ws + 2048;
    int*   ss   = (int*)(ws + 3088);

    // Stage weights once (L3-broadcast, 16 KB).
    for (int i = t; i < NHID * NCH; i += NT) { sW1[i] = W1[i]; sW2[i] = W2[i]; }
    if (t < NHID) sb1[t] = b1[t];
    if (t < NCH)  sb2[t] = b2[t];

    // Init stats + segment-start table (block 0), then make visible.
    if (blk == 0) {
        for (int i = t; i < 1024; i += NT) { wsum[i] = 0.0f; wmax[i] = -INFINITY; }
        if (t < NBAT) wcnt[t] = 0.0f;
        if (t < NBAT) ss[t] = INT_MAX;
    }
    grid.sync();

    // Scan sorted batch_ids for segment starts (16 MB of reads, ~2.5 us).
    for (int i = blk * NT + t; i < n; i += NB * NT) {
        const int b = bid[i];
        if (i == 0) atomicMin(&ss[b], 0);
        else if (bid[i - 1] != b) atomicMin(&ss[b], i);
    }
    grid.sync();

    const int c4 = t & 15;   // channel group (float4)
    const int rg = t >> 4;   // row group (64 in flight)

    for (int g = 0; g < NGRP; ++g) {
        const int gb = min(minseg(ss, g * SPG, n), n);
        const int ge = min(minseg(ss, g * SPG + SPG, n), n);
        const int rows = ge - gb;
        const int rpb  = rows > 0 ? (rows + NB - 1) / NB : 0;
        const int r0   = gb + blk * rpb;
        const int rend = min(r0 + rpb, ge);

        // ---- pool own slice ----
        int cur = -1;
        float4 s = make_float4(0.f, 0.f, 0.f, 0.f);
        float4 m = make_float4(-INFINITY, -INFINITY, -INFINITY, -INFINITY);
        float cnt = 0.0f;
        for (int r = r0 + rg; r < rend; r += 64) {
            const int b = bid[r];
            if (b != cur) {
                if (cur >= 0) flush_seg(wsum, wmax, wcnt, cur, c4, s, m, cnt);
                cur = b;
                s = make_float4(0.f, 0.f, 0.f, 0.f);
                m = make_float4(-INFINITY, -INFINITY, -INFINITY, -INFINITY);
                cnt = 0.0f;
            }
            const float4 v = *reinterpret_cast<const float4*>(x + (size_t)r * NCH + c4 * 4);
            s.x += v.x; s.y += v.y; s.z += v.z; s.w += v.w;
            m.x = fmaxf(m.x, v.x); m.y = fmaxf(m.y, v.y);
            m.z = fmaxf(m.z, v.z); m.w = fmaxf(m.w, v.w);
            cnt += 1.0f;
        }
        // Block combine across the 64 row groups (same c4).
        lb[t] = cur; ls[t] = s; lm[t] = m; lc[t] = cnt;
        __syncthreads();
        if (rg == 0) {
            for (int gg = 1; gg < 64; ++gg) {
                const int i = gg * 16 + c4;
                const int ob = lb[i];
                if (ob < 0) continue;
                if (ob == cur && cur >= 0) {
                    const float4 os = ls[i]; const float4 om = lm[i];
                    s.x += os.x; s.y += os.y; s.z += os.z; s.w += os.w;
                    m.x = fmaxf(m.x, om.x); m.y = fmaxf(m.y, om.y);
                    m.z = fmaxf(m.z, om.z); m.w = fmaxf(m.w, om.w);
                    cnt += lc[i];
                } else if (cur < 0) {
                    cur = ob; s = ls[i]; m = lm[i]; cnt = lc[i];
                } else {
                    flush_seg(wsum, wmax, wcnt, ob, c4, ls[i], lm[i], lc[i]);
                }
            }
            if (cur >= 0) flush_seg(wsum, wmax, wcnt, cur, c4, s, m, cnt);
        }
        grid.sync();  // group-g stats complete, device-visible

        // ---- tiny MLP, redundant per block, in LDS (reuses ls region) ----
        float* avg = (float*)ls;          // 256 floats
        float* mxs = avg + SPG * NCH;     // 256
        float* h1a = mxs + SPG * NCH;     // 128
        float* h1m = h1a + SPG * NHID;    // 128
        if (t < SPG * NCH) {
            const int b = g * SPG + (t >> 6);
            const float c = wcnt[b];
            avg[t] = wsum[b * NCH + (t & 63)] / fmaxf(c, 1.0f);
            mxs[t] = wmax[b * NCH + (t & 63)];
        }
        __syncthreads();
        if (t < SPG * NHID) {
            const int bb = t >> 5, j = t & 31;
            float sa = sb1[j], sm = sb1[j];
            const float* w = &sW1[j * NCH];
            for (int c = 0; c < NCH; ++c) {
                const float wv = w[c];
                sa += avg[bb * NCH + c] * wv;
                sm += mxs[bb * NCH + c] * wv;
            }
            h1a[t] = fmaxf(sa, 0.0f);
            h1m[t] = fmaxf(sm, 0.0f);
        }
        __syncthreads();
        if (t < SPG * NCH) {
            const int bb = t >> 6, c = t & 63;
            float ya = sb2[c], ym = sb2[c];
            const float* w = &sW2[c * NHID];
            for (int j = 0; j < NHID; ++j) {
                const float wv = w[j];
                ya += h1a[bb * NHID + j] * wv;
                ym += h1m[bb * NHID + j] * wv;
            }
            const float z = ya + ym;
            sscale[t] = 1.0f + 1.0f / (1.0f + expf(-z));  // out = x*(1+att)
        }
        __syncthreads();

        // ---- apply own slice (rows just read by this CU -> L2/L3 hits) ----
        // scale index: bid in [4g, 4g+4) -> bid & 3.
        int r = r0 + rg;
        for (; r + 64 < rend; r += 128) {
            const int b0 = bid[r] & 3;
            const int b1i = bid[r + 64] & 3;
            const f4 v0 = *reinterpret_cast<const f4*>(x + (size_t)r * NCH + c4 * 4);
            const f4 v1 = *reinterpret_cast<const f4*>(x + (size_t)(r + 64) * NCH + c4 * 4);
            const f4 s0 = *reinterpret_cast<const f4*>(&sscale[b0 * NCH + c4 * 4]);
            const f4 s1 = *reinterpret_cast<const f4*>(&sscale[b1i * NCH + c4 * 4]);
            const f4 o0 = v0 * s0;
            const f4 o1 = v1 * s1;
            __builtin_nontemporal_store(o0, reinterpret_cast<f4*>(out + (size_t)r * NCH + c4 * 4));
            __builtin_nontemporal_store(o1, reinterpret_cast<f4*>(out + (size_t)(r + 64) * NCH + c4 * 4));
        }
        for (; r < rend; r += 64) {
            const int b = bid[r] & 3;
            const f4 v  = *reinterpret_cast<const f4*>(x + (size_t)r * NCH + c4 * 4);
            const f4 sc = *reinterpret_cast<const f4*>(&sscale[b * NCH + c4 * 4]);
            const f4 o = v * sc;
            __builtin_nontemporal_store(o, reinterpret_cast<f4*>(out + (size_t)r * NCH + c4 * 4));
        }
        // No sync needed before next group's pool: ls/lb writes happen after
        // this block's own apply, and no cross-block LDS visibility exists.
    }
}

extern "C" void kernel_launch(void* const* d_in, const int* in_sizes, int n_in,
                              void* d_out, int out_size, void* d_ws, size_t ws_size,
                              hipStream_t stream) {
    const float* x   = (const float*)d_in[0];
    const int*   bid = (const int*)d_in[1];
    const float* W1  = (const float*)d_in[2];
    const float* b1  = (const float*)d_in[3];
    const float* W2  = (const float*)d_in[4];
    const float* b2  = (const float*)d_in[5];
    float* out = (float*)d_out;
    float* ws  = (float*)d_ws;
    int n = in_sizes[1];  // N (batch_ids element count)

    void* args[] = { (void*)&x, (void*)&bid, (void*)&W1, (void*)&b1,
                     (void*)&W2, (void*)&b2, (void*)&out, (void*)&ws, (void*)&n };
    hipLaunchCooperativeKernel((const void*)fused_kernel, dim3(NB), dim3(NT),
                               args, 0, stream);
}